// Round 5
// baseline (290.065 us; speedup 1.0000x reference)
//
#include <hip/hip_runtime.h>
#include <cstdint>

// MoE: B=16384 rows, D=2048 feat, E=16 experts, C=64 classes/expert.
// R8: R7 = 283us, but top-5 is all harness poison-fill (78us fixed tax) and
// budget math says coarse+expert burn ~185us vs ~35us roofline. Prime
// suspect: expert_gemm loads B (ewH/L, 8 loads/chunk) INSIDE the ct-loop
// with immediate MFMA use -> ~200cyc L2 stall per ct group at only
// 2 waves/SIMD (acc=64 VGPR puts it in the 129-256 band). Fix: full
// next-chunk register prefetch of B (bhn/bln arrays, +32 VGPR, same
// occupancy band = free) to match the existing A prefetch; every chunk's
// loads now fly under ~550cyc of conv+MFMA. Also: make_schedule fused into
// route_build (last-done block builds it; threadfence + atomic reads),
// saving one serialized launch.
// f16x3 scheme (R6/R7-proven): a = hi + lo*2^-11, lo prescaled by 2048;
// accH = hi*hi, accC = hi*lo' + lo'*hi; y = accH + accC/2048.
// Fragment convention (R6/R7-validated): A/B frag = 8 contiguous k at
// row/col (lane&15), k-base (lane>>4)*8; D element = (row=(lane>>4)*4+reg,
// col=lane&15).
typedef _Float16 f16;
typedef f16 f16x8 __attribute__((ext_vector_type(8)));
typedef float f32x4 __attribute__((ext_vector_type(4)));
#define MFMA16(a, b, c) __builtin_amdgcn_mfma_f32_16x16x32_f16((a), (b), (c), 0, 0, 0)

static constexpr int B_ = 16384;
static constexpr int D_ = 2048;
static constexpr int E_ = 16;
static constexpr int C_ = 64;
static constexpr float LSC = 2048.0f;   // lo-term scale (2^11)
static constexpr float ILSC = 1.0f / 2048.0f;
static constexpr int TR_E = 128;        // expert tile rows
static constexpr int SK_E = 8;          // expert split-K
static constexpr int MAXITEMS = (B_ / TR_E) + E_;  // 144 worst case

// f32 -> (hi f16, lo f16 prescaled by 2048). Bitwise identical to R6/R7.
__device__ __forceinline__ void cvt_hl(const float4 x, const float4 y,
                                       f16x8& h, f16x8& l) {
  const float av[8] = {x.x, x.y, x.z, x.w, y.x, y.y, y.z, y.w};
#pragma unroll
  for (int j = 0; j < 8; ++j) {
    const f16 hh = (f16)av[j];
    h[j] = hh;
    l[j] = (f16)((av[j] - (float)hh) * LSC);
  }
}

// ---- one-shot weight conversion (cw 128KB + ew 8MB of f16 out, ~4us) ----
__global__ __launch_bounds__(256) void convert_w(
    const float* __restrict__ cw, const float* __restrict__ ew,
    f16* __restrict__ cwH, f16* __restrict__ cwL,
    f16* __restrict__ ewH, f16* __restrict__ ewL) {
  const int g = blockIdx.x;
  const int tid = threadIdx.x;
  const float* src;
  f16 *dh, *dl;
  size_t off;
  if (g < 16) {  // cw: 16*2048 elems
    off = ((size_t)g * 256 + tid) * 8;
    src = cw; dh = cwH; dl = cwL;
  } else {       // ew: 16*64*2048 elems
    off = ((size_t)(g - 16) * 256 + tid) * 8;
    src = ew; dh = ewH; dl = ewL;
  }
  const float4 v0 = *(const float4*)(src + off);
  const float4 v1 = *(const float4*)(src + off + 4);
  f16x8 h8, l8;
  cvt_hl(v0, v1, h8, l8);
  *(f16x8*)(dh + off) = h8;
  *(f16x8*)(dl + off) = l8;
}

// ---- coarse: f32 feat read ONCE, f16x3 MFMA, fused bias+argmax ----
// 1024 blocks x 512 thr (8 waves). Block owns 16 rows; wave w owns K-range
// [w*256, (w+1)*256) as 8 chunks of 32. No K-loop stores; A+B prefetched one
// chunk ahead. 8 partial C tiles reduced through 8KB LDS; epilogue argmax.
// VGPR ~48 -> 8 waves/SIMD; unchanged from R7 (the control this round).
__global__ __launch_bounds__(512) void coarse_fused(
    const float* __restrict__ feat, const f16* __restrict__ cwH,
    const f16* __restrict__ cwL, const float* __restrict__ cb,
    float* __restrict__ out0, float* __restrict__ out1,
    int* __restrict__ eidArr) {
  __shared__ float red[8 * 256];  // [wave][localrow*16 + e]
  const int tid = threadIdx.x;
  const int w = tid >> 6;
  const int lane = tid & 63;
  const int rl = lane & 15;   // feat row within block / expert col
  const int kq = lane >> 4;   // k-quad
  const int row = blockIdx.x * 16 + rl;
  const int k0 = w * (D_ / 8);

  const float* fr = feat + (size_t)row * D_ + k0 + kq * 8;
  const f16* bhp = cwH + (size_t)rl * D_ + k0 + kq * 8;
  const f16* blp = cwL + (size_t)rl * D_ + k0 + kq * 8;

  f32x4 aH = {0.f, 0.f, 0.f, 0.f};
  f32x4 aC = {0.f, 0.f, 0.f, 0.f};

  // prefetch chunk 0
  float4 v0 = *(const float4*)(fr);
  float4 v1 = *(const float4*)(fr + 4);
  f16x8 bhn = *(const f16x8*)(bhp);
  f16x8 bln = *(const f16x8*)(blp);
#pragma unroll
  for (int ch = 0; ch < 8; ++ch) {
    const float4 c0 = v0, c1 = v1;
    const f16x8 bh = bhn, bl = bln;
    if (ch + 1 < 8) {  // issue next chunk's loads early
      const int ko = (ch + 1) * 32;
      v0 = *(const float4*)(fr + ko);
      v1 = *(const float4*)(fr + ko + 4);
      bhn = *(const f16x8*)(bhp + ko);
      bln = *(const f16x8*)(blp + ko);
    }
    f16x8 h8, l8;
    cvt_hl(c0, c1, h8, l8);
    aH = MFMA16(h8, bh, aH);
    aC = MFMA16(h8, bl, aC);
    aC = MFMA16(l8, bh, aC);
  }
#pragma unroll
  for (int reg = 0; reg < 4; ++reg)
    red[w * 256 + (kq * 4 + reg) * 16 + rl] = aH[reg] + aC[reg] * ILSC;
  __syncthreads();

  if (tid < 256) {
    const int e = tid & 15;
    const int lrow = tid >> 4;
    float val = cb[e];
#pragma unroll
    for (int ww = 0; ww < 8; ++ww) val += red[ww * 256 + tid];
    const int grow = blockIdx.x * 16 + lrow;
    out0[(size_t)grow * E_ + e] = val;
    // argmax over 16 experts (16-lane group), first-occurrence tie-break
    float av2 = val;
    int ai = e;
#pragma unroll
    for (int off = 8; off; off >>= 1) {
      const float ov = __shfl_xor(av2, off, 16);
      const int oi = __shfl_xor(ai, off, 16);
      if (ov > av2 || (ov == av2 && oi < ai)) { av2 = ov; ai = oi; }
    }
    if (e == 0) {
      out1[grow] = (float)ai;
      eidArr[grow] = ai;
    }
  }
}

// ---- routing compaction + (fused) schedule build ----
// Block-aggregated atomics (R3-proven). The LAST block to finish (device
// atomic doneCnt) builds the dense (e,tile) worker list, replacing the
// separate make_schedule launch. cnt reads via atomicAdd(.,0) for coherence.
__global__ __launch_bounds__(256) void route_build(
    const int* __restrict__ eidArr, int* __restrict__ cnt,
    int* __restrict__ rowList, int* __restrict__ sched,
    int* __restrict__ nItems, int* __restrict__ doneCnt) {
  __shared__ int lcnt[E_];
  __shared__ int lbase[E_];
  __shared__ int tiles[E_];
  __shared__ int offs[E_];
  __shared__ int isLast;
  const int tid = threadIdx.x;
  if (tid < E_) lcnt[tid] = 0;
  __syncthreads();
  const int row = blockIdx.x * 256 + tid;
  const int best = eidArr[row];
  const int lpos = atomicAdd(&lcnt[best], 1);
  __syncthreads();
  if (tid < E_) lbase[tid] = atomicAdd(&cnt[tid], lcnt[tid]);
  __syncthreads();
  rowList[best * B_ + lbase[best] + lpos] = row;

  // ---- last-done block builds the schedule ----
  __syncthreads();
  if (tid == 0) {
    __threadfence();  // make this block's cnt atomics + rowList visible
    const int d = atomicAdd(doneCnt, 1);
    isLast = (d == (int)gridDim.x - 1) ? 1 : 0;
  }
  __syncthreads();
  if (isLast) {
    if (tid < E_)
      tiles[tid] = (atomicAdd(&cnt[tid], 0) + TR_E - 1) / TR_E;
    __syncthreads();
    if (tid == 0) {
      int acc = 0;
      for (int e2 = 0; e2 < E_; ++e2) { offs[e2] = acc; acc += tiles[e2]; }
      *nItems = acc;
    }
    __syncthreads();
    if (tid < E_) {
      const int o = offs[tid], n = tiles[tid];
      for (int k = 0; k < n; ++k) sched[o + k] = tid | (k << 8);
    }
  }
}

// ---- expert GEMM: f16x3 MFMA; A from f32 feat (L3-warm) converted on the
// fly; BOTH A and B prefetched one full chunk ahead in registers ----
__global__ __launch_bounds__(256) void expert_gemm(
    const float* __restrict__ feat,
    const f16* __restrict__ ewH, const f16* __restrict__ ewL,
    const int* __restrict__ rowList, const int* __restrict__ cnt,
    const int* __restrict__ sched, const int* __restrict__ nItems,
    float* __restrict__ part0, float* __restrict__ partRest) {
  __shared__ int rIdx[TR_E];
  const int b = blockIdx.x;
  const int kz = b % SK_E;
  const int item = b / SK_E;
  if (item >= *nItems) return;  // uniform per block, before any barrier
  const int s = sched[item];
  const int e = s & 255;
  const int tile = s >> 8;
  const int count = cnt[e];

  const int tid = threadIdx.x;
  if (tid < TR_E) {
    const int slot = tile * TR_E + tid;
    rIdx[tid] = (slot < count) ? rowList[e * B_ + slot] : 0;
  }
  __syncthreads();

  const int lane = tid & 63;
  const int w = tid >> 6;
  const int rl = lane & 15;
  const int kq = lane >> 4;

  const int grow0 = rIdx[w * 32 + rl];
  const int grow1 = rIdx[w * 32 + 16 + rl];
  constexpr int KRANGE = D_ / SK_E;  // 256
  constexpr int NCH = KRANGE / 32;   // 8
  const int k0 = kz * KRANGE;

  const float* pa0 = feat + (size_t)grow0 * D_ + k0 + kq * 8;
  const float* pa1 = feat + (size_t)grow1 * D_ + k0 + kq * 8;
  const size_t eoff = (size_t)e * C_ * D_;
  const f16* pbh[4];
  const f16* pbl[4];
#pragma unroll
  for (int ct = 0; ct < 4; ++ct) {
    const size_t co = eoff + (size_t)(ct * 16 + rl) * D_ + k0 + kq * 8;
    pbh[ct] = ewH + co;
    pbl[ct] = ewL + co;
  }

  f32x4 accH[2][4], accC[2][4];
#pragma unroll
  for (int s2 = 0; s2 < 2; ++s2)
#pragma unroll
    for (int ct = 0; ct < 4; ++ct) {
      accH[s2][ct] = (f32x4){0.f, 0.f, 0.f, 0.f};
      accC[s2][ct] = (f32x4){0.f, 0.f, 0.f, 0.f};
    }

  // prefetch chunk 0: A (f32) and B (f16 h/l) into registers
  float4 n0a = *(const float4*)(pa0);
  float4 n0b = *(const float4*)(pa0 + 4);
  float4 n1a = *(const float4*)(pa1);
  float4 n1b = *(const float4*)(pa1 + 4);
  f16x8 bhn[4], bln[4];
#pragma unroll
  for (int ct = 0; ct < 4; ++ct) {
    bhn[ct] = *(const f16x8*)(pbh[ct]);
    bln[ct] = *(const f16x8*)(pbl[ct]);
  }
#pragma unroll
  for (int ch = 0; ch < NCH; ++ch) {
    const float4 c0a = n0a, c0b = n0b, c1a = n1a, c1b = n1b;
    f16x8 bhc[4], blc[4];
#pragma unroll
    for (int ct = 0; ct < 4; ++ct) { bhc[ct] = bhn[ct]; blc[ct] = bln[ct]; }
    if (ch + 1 < NCH) {  // issue ALL of next chunk's loads before compute
      const int kn = (ch + 1) * 32;
      n0a = *(const float4*)(pa0 + kn);
      n0b = *(const float4*)(pa0 + kn + 4);
      n1a = *(const float4*)(pa1 + kn);
      n1b = *(const float4*)(pa1 + kn + 4);
#pragma unroll
      for (int ct = 0; ct < 4; ++ct) {
        bhn[ct] = *(const f16x8*)(pbh[ct] + kn);
        bln[ct] = *(const f16x8*)(pbl[ct] + kn);
      }
    }
    f16x8 a0h, a0l, a1h, a1l;
    cvt_hl(c0a, c0b, a0h, a0l);
    cvt_hl(c1a, c1b, a1h, a1l);
#pragma unroll
    for (int ct = 0; ct < 4; ++ct) {
      accH[0][ct] = MFMA16(a0h, bhc[ct], accH[0][ct]);
      accC[0][ct] = MFMA16(a0h, blc[ct], accC[0][ct]);
      accC[0][ct] = MFMA16(a0l, bhc[ct], accC[0][ct]);
      accH[1][ct] = MFMA16(a1h, bhc[ct], accH[1][ct]);
      accC[1][ct] = MFMA16(a1h, blc[ct], accC[1][ct]);
      accC[1][ct] = MFMA16(a1l, bhc[ct], accC[1][ct]);
    }
  }

  float* pk = kz ? (partRest + (size_t)(kz - 1) * B_ * C_) : part0;
#pragma unroll
  for (int s2 = 0; s2 < 2; ++s2)
#pragma unroll
    for (int reg = 0; reg < 4; ++reg) {
      const int rloc = w * 32 + s2 * 16 + kq * 4 + reg;
      const int slot = tile * TR_E + rloc;
      if (slot < count) {
        const int g = rIdx[rloc];
#pragma unroll
        for (int ct = 0; ct < 4; ++ct)
          pk[(size_t)g * C_ + ct * 16 + rl] =
              accH[s2][ct][reg] + accC[s2][ct][reg] * ILSC;
      }
    }
}

// ---- wave-per-row: reduce y partials (fixed order), bias, softmax, argmax ----
template <int SK>
__global__ __launch_bounds__(256) void finish_rows(
    const float* __restrict__ ypart0, const float* __restrict__ ypartRest,
    const float* __restrict__ eb, const int* __restrict__ eidArr,
    float* __restrict__ out2, float* __restrict__ out3) {
  const int lane = threadIdx.x & 63;
  const int row = (blockIdx.x * 256 + threadIdx.x) >> 6;
  const int eid = eidArr[row];

  float v = eb[eid * C_ + lane];
  v += ypart0[(size_t)row * C_ + lane];
#pragma unroll
  for (int kz = 1; kz < SK; ++kz)
    v += ypartRest[((size_t)(kz - 1) * B_ + row) * C_ + lane];

  float m = v;
#pragma unroll
  for (int off = 32; off; off >>= 1) m = fmaxf(m, __shfl_xor(m, off, 64));
  const float p = __expf(v - m);
  float s = p;
#pragma unroll
  for (int off = 32; off; off >>= 1) s += __shfl_xor(s, off, 64);
  out2[(size_t)row * C_ + lane] = p / s;  // ypart0 aliases out2; read done

  float av = v;
  int ai = lane;
#pragma unroll
  for (int off = 32; off; off >>= 1) {
    const float ov = __shfl_xor(av, off, 64);
    const int oi = __shfl_xor(ai, off, 64);
    if (ov > av || (ov == av && oi < ai)) { av = ov; ai = oi; }
  }
  if (lane == 0) out3[row] = (float)(ai + (eid << 6));
}

extern "C" void kernel_launch(void* const* d_in, const int* in_sizes, int n_in,
                              void* d_out, int out_size, void* d_ws,
                              size_t ws_size, hipStream_t stream) {
  const float* feat = (const float*)d_in[0];  // [B, D]
  const float* cw = (const float*)d_in[1];    // [E, D]
  const float* cb = (const float*)d_in[2];    // [E]
  const float* ew = (const float*)d_in[3];    // [E, C, D]
  const float* eb = (const float*)d_in[4];    // [E, C]

  float* out0 = (float*)d_out;           // coarse_output [B, E]
  float* out1 = out0 + (size_t)B_ * E_;  // expert_id [B] (as float)
  float* out2 = out1 + B_;               // local_preds [B, C]
  float* out3 = out2 + (size_t)B_ * C_;  // global_preds [B]

  // ws (~40 MB): f16 weights + kz>=1 y-partials + routing metadata.
  char* p = (char*)d_ws;
  f16* ewH = (f16*)p;        p += (size_t)E_ * C_ * D_ * 2;       // 4 MB
  f16* ewL = (f16*)p;        p += (size_t)E_ * C_ * D_ * 2;       // 4 MB
  f16* cwH = (f16*)p;        p += (size_t)E_ * D_ * 2;            // 64 KB
  f16* cwL = (f16*)p;        p += (size_t)E_ * D_ * 2;            // 64 KB
  float* ypartRest = (float*)p; p += (size_t)(SK_E - 1) * B_ * C_ * 4;  // 29.4 MB
  int* rowList = (int*)p;    p += (size_t)E_ * B_ * 4;            // 1 MB
  int* cnt = (int*)p;        p += 64 * 4;   // cnt[0..15], doneCnt = cnt[16]
  int* eidArr = (int*)p;     p += (size_t)B_ * 4;
  int* sched = (int*)p;      p += 512 * 4;
  int* nItems = (int*)p;
  int* doneCnt = cnt + 16;

  hipMemsetAsync(cnt, 0, 32 * sizeof(int), stream);

  // 1) weights -> f16 hi/lo (8.5 MB out, ~4 us)
  convert_w<<<16 + 1024, 256, 0, stream>>>(cw, ew, cwH, cwL, ewH, ewL);
  // 2) coarse MFMA + argmax (134 MB streamed; 1024 blocks, 32 waves/CU)
  coarse_fused<<<B_ / 16, 512, 0, stream>>>(feat, cwH, cwL, cb, out0, out1,
                                            eidArr);
  // 3) routing compaction + fused schedule build (last-done block)
  route_build<<<B_ / 256, 256, 0, stream>>>(eidArr, cnt, rowList, sched,
                                            nItems, doneCnt);
  // 4) expert MFMA GEMM (<=144 items * SK 8 = 1152 blocks)
  expert_gemm<<<MAXITEMS * SK_E, 256, 0, stream>>>(
      feat, ewH, ewL, rowList, cnt, sched, nItems, out2, ypartRest);
  // 5) softmax + argmax + class-range start
  finish_rows<SK_E><<<(B_ * 64) / 256, 256, 0, stream>>>(out2, ypartRest, eb,
                                                         eidArr, out2, out3);
}